// Round 1
// baseline (156.827 us; speedup 1.0000x reference)
//
#include <hip/hip_runtime.h>

#define IMG_H 512
#define IMG_W 512
#define NB    32
#define HW    (IMG_H * IMG_W)

// Each thread: one 8-pixel horizontal segment of one image.
// Segments per image: 512 rows * 64 segs/row = 32768. Block=256 -> grid.x=128, grid.y=B.
__global__ __launch_bounds__(256) void iou_kernel(const float* __restrict__ yhat,
                                                  const int* __restrict__ y,
                                                  unsigned long long* __restrict__ counts) {
    const int b   = blockIdx.y;
    const int tid = blockIdx.x * 256 + threadIdx.x;      // segment id within image
    const int h     = tid >> 6;                           // / 64
    const int wbase = (tid & 63) << 3;                    // * 8

    const int* yb = y + (size_t)b * HW;

    // Column predicates over 10 columns (image cols wbase-1 .. wbase+8), bit j = col wbase-1+j.
    // AND identity = 1 (erode border +inf), OR identity = 0 (dilate border -inf).
    unsigned and1 = 0x3FFu, or1 = 0u, and2 = 0x3FFu, or2 = 0u;

    unsigned validcols = 0x3FFu;
    if (wbase == 0)            validcols &= ~1u;          // col -1 OOB
    if (wbase + 8 >= IMG_W)    validcols &= ~(1u << 9);   // col W OOB
    const unsigned invalidcols = ~validcols;

    #pragma unroll
    for (int dr = -1; dr <= 1; ++dr) {
        const int r = h + dr;
        if (r < 0 || r >= IMG_H) continue;                // OOB row -> identities (no-op)
        const int* row = yb + r * IMG_W + wbase;
        int c[10];
        c[0] = (wbase > 0) ? row[-1] : -1;
        const int4 v0 = *reinterpret_cast<const int4*>(row);
        const int4 v1 = *reinterpret_cast<const int4*>(row + 4);
        c[1] = v0.x; c[2] = v0.y; c[3] = v0.z; c[4] = v0.w;
        c[5] = v1.x; c[6] = v1.y; c[7] = v1.z; c[8] = v1.w;
        c[9] = (wbase + 8 < IMG_W) ? row[8] : -1;
        unsigned m1 = 0u, m2 = 0u;
        #pragma unroll
        for (int j = 0; j < 10; ++j) {
            m1 |= (c[j] == 1) ? (1u << j) : 0u;
            m2 |= (c[j] == 2) ? (1u << j) : 0u;
        }
        and1 &= (m1 | invalidcols);
        and2 &= (m2 | invalidcols);
        or1  |= (m1 & validcols);
        or2  |= (m2 & validcols);
    }

    // Horizontal 3-wide combine: pixel j uses column bits j, j+1, j+2.
    const unsigned E1 = and1 & (and1 >> 1) & (and1 >> 2);
    const unsigned E2 = and2 & (and2 >> 1) & (and2 >> 2);
    const unsigned D1 = or1  | (or1  >> 1) | (or1  >> 2);
    const unsigned D2 = or2  | (or2  >> 1) | (or2  >> 2);

    // Argmax over 3 channels (first-occurrence ties: strict > for later channels).
    const float* yh = yhat + (size_t)b * 3 * HW + (size_t)h * IMG_W + wbase;
    const float4 a0 = *reinterpret_cast<const float4*>(yh);
    const float4 a1 = *reinterpret_cast<const float4*>(yh + 4);
    const float4 b0 = *reinterpret_cast<const float4*>(yh + HW);
    const float4 b1 = *reinterpret_cast<const float4*>(yh + HW + 4);
    const float4 c0 = *reinterpret_cast<const float4*>(yh + 2 * HW);
    const float4 c1 = *reinterpret_cast<const float4*>(yh + 2 * HW + 4);
    float va[8] = {a0.x, a0.y, a0.z, a0.w, a1.x, a1.y, a1.z, a1.w};
    float vb[8] = {b0.x, b0.y, b0.z, b0.w, b1.x, b1.y, b1.z, b1.w};
    float vc[8] = {c0.x, c0.y, c0.z, c0.w, c1.x, c1.y, c1.z, c1.w};

    unsigned inter = 0u, uni = 0u;
    #pragma unroll
    for (int j = 0; j < 8; ++j) {
        int   prob = 0;
        float best = va[j];
        if (vb[j] > best) { best = vb[j]; prob = 1; }
        if (vc[j] > best) {               prob = 2; }

        const int e1b = (E1 >> j) & 1;
        const int e2b = (E2 >> j) & 1;
        const int d1b = (D1 >> j) & 1;
        const int d2b = (D2 >> j) & 1;

        const int ero = e2b ? 2 : e1b;   // class 2 overrides class 1
        const int dil = d2b ? 2 : d1b;

        inter += (unsigned)((dil != 0) & (dil == prob));
        uni   += (unsigned)((ero != 0) | (prob != 0));
    }

    // Wave-64 reduce of packed (uni<<32 | inter), then one atomic per wave.
    unsigned long long packed = (unsigned long long)inter | ((unsigned long long)uni << 32);
    #pragma unroll
    for (int off = 32; off > 0; off >>= 1)
        packed += __shfl_down(packed, off, 64);
    if ((threadIdx.x & 63) == 0)
        atomicAdd(&counts[b], packed);
}

__global__ void finalize_kernel(const unsigned long long* __restrict__ counts,
                                float* __restrict__ out) {
    const int lane = threadIdx.x;
    float s = 0.0f;
    if (lane < NB) {
        const unsigned long long p = counts[lane];
        const float inter = (float)(unsigned int)(p & 0xFFFFFFFFull);
        const float uni   = (float)(unsigned int)(p >> 32);
        s = inter / uni;
    }
    #pragma unroll
    for (int off = 32; off > 0; off >>= 1)
        s += __shfl_down(s, off, 64);
    if (lane == 0)
        out[0] = s / (float)NB;
}

extern "C" void kernel_launch(void* const* d_in, const int* in_sizes, int n_in,
                              void* d_out, int out_size, void* d_ws, size_t ws_size,
                              hipStream_t stream) {
    const float* yhat = (const float*)d_in[0];
    const int*   y    = (const int*)d_in[1];
    float*       out  = (float*)d_out;
    unsigned long long* counts = (unsigned long long*)d_ws;

    hipMemsetAsync(d_ws, 0, NB * sizeof(unsigned long long), stream);

    dim3 grid(128, NB, 1);
    iou_kernel<<<grid, 256, 0, stream>>>(yhat, y, counts);
    finalize_kernel<<<1, 64, 0, stream>>>(counts, out);
}

// Round 2
// 37.557 us; speedup vs baseline: 4.1757x; 4.1757x over previous
//
#include <hip/hip_runtime.h>

#define IMG_H 512
#define IMG_W 512
#define NB    32
#define HW    (IMG_H * IMG_W)
#define CSTRIDE 16   // u64 per counter slot -> 128 B = 1 cacheline per batch counter

// Each thread: one 8-pixel horizontal segment of one image.
// Segments per image: 512 rows * 64 segs/row = 32768. Block=256 -> grid.x=128, grid.y=B.
__global__ __launch_bounds__(256) void iou_kernel(const float* __restrict__ yhat,
                                                  const int* __restrict__ y,
                                                  unsigned long long* __restrict__ counts) {
    const int b   = blockIdx.y;
    const int tid = blockIdx.x * 256 + threadIdx.x;      // segment id within image
    const int h     = tid >> 6;                           // / 64
    const int wbase = (tid & 63) << 3;                    // * 8

    const int* yb = y + (size_t)b * HW;

    // Column predicates over 10 columns (image cols wbase-1 .. wbase+8), bit j = col wbase-1+j.
    // AND identity = 1 (erode border +inf), OR identity = 0 (dilate border -inf).
    unsigned and1 = 0x3FFu, or1 = 0u, and2 = 0x3FFu, or2 = 0u;

    unsigned validcols = 0x3FFu;
    if (wbase == 0)            validcols &= ~1u;          // col -1 OOB
    if (wbase + 8 >= IMG_W)    validcols &= ~(1u << 9);   // col W OOB
    const unsigned invalidcols = ~validcols;

    #pragma unroll
    for (int dr = -1; dr <= 1; ++dr) {
        const int r = h + dr;
        if (r < 0 || r >= IMG_H) continue;                // OOB row -> identities (no-op)
        const int* row = yb + r * IMG_W + wbase;
        int c[10];
        c[0] = (wbase > 0) ? row[-1] : -1;
        const int4 v0 = *reinterpret_cast<const int4*>(row);
        const int4 v1 = *reinterpret_cast<const int4*>(row + 4);
        c[1] = v0.x; c[2] = v0.y; c[3] = v0.z; c[4] = v0.w;
        c[5] = v1.x; c[6] = v1.y; c[7] = v1.z; c[8] = v1.w;
        c[9] = (wbase + 8 < IMG_W) ? row[8] : -1;
        unsigned m1 = 0u, m2 = 0u;
        #pragma unroll
        for (int j = 0; j < 10; ++j) {
            m1 |= (c[j] == 1) ? (1u << j) : 0u;
            m2 |= (c[j] == 2) ? (1u << j) : 0u;
        }
        and1 &= (m1 | invalidcols);
        and2 &= (m2 | invalidcols);
        or1  |= (m1 & validcols);
        or2  |= (m2 & validcols);
    }

    // Horizontal 3-wide combine: pixel j uses column bits j, j+1, j+2.
    const unsigned E1 = and1 & (and1 >> 1) & (and1 >> 2);
    const unsigned E2 = and2 & (and2 >> 1) & (and2 >> 2);
    const unsigned D1 = or1  | (or1  >> 1) | (or1  >> 2);
    const unsigned D2 = or2  | (or2  >> 1) | (or2  >> 2);

    // Argmax over 3 channels (first-occurrence ties: strict > for later channels).
    const float* yh = yhat + (size_t)b * 3 * HW + (size_t)h * IMG_W + wbase;
    const float4 a0 = *reinterpret_cast<const float4*>(yh);
    const float4 a1 = *reinterpret_cast<const float4*>(yh + 4);
    const float4 b0 = *reinterpret_cast<const float4*>(yh + HW);
    const float4 b1 = *reinterpret_cast<const float4*>(yh + HW + 4);
    const float4 c0 = *reinterpret_cast<const float4*>(yh + 2 * HW);
    const float4 c1 = *reinterpret_cast<const float4*>(yh + 2 * HW + 4);
    float va[8] = {a0.x, a0.y, a0.z, a0.w, a1.x, a1.y, a1.z, a1.w};
    float vb[8] = {b0.x, b0.y, b0.z, b0.w, b1.x, b1.y, b1.z, b1.w};
    float vc[8] = {c0.x, c0.y, c0.z, c0.w, c1.x, c1.y, c1.z, c1.w};

    unsigned inter = 0u, uni = 0u;
    #pragma unroll
    for (int j = 0; j < 8; ++j) {
        int   prob = 0;
        float best = va[j];
        if (vb[j] > best) { best = vb[j]; prob = 1; }
        if (vc[j] > best) {               prob = 2; }

        const int e1b = (E1 >> j) & 1;
        const int e2b = (E2 >> j) & 1;
        const int d1b = (D1 >> j) & 1;
        const int d2b = (D2 >> j) & 1;

        const int ero = e2b ? 2 : e1b;   // class 2 overrides class 1
        const int dil = d2b ? 2 : d1b;

        inter += (unsigned)((dil != 0) & (dil == prob));
        uni   += (unsigned)((ero != 0) | (prob != 0));
    }

    // Wave-64 reduce of packed (uni<<32 | inter).
    unsigned long long packed = (unsigned long long)inter | ((unsigned long long)uni << 32);
    #pragma unroll
    for (int off = 32; off > 0; off >>= 1)
        packed += __shfl_down(packed, off, 64);

    // Block-level reduce in LDS: 4 waves -> ONE atomic per block, to a
    // cacheline-padded per-batch counter (kills memory-side atomic serialization).
    __shared__ unsigned long long part[4];
    const int wave = threadIdx.x >> 6;
    if ((threadIdx.x & 63) == 0)
        part[wave] = packed;
    __syncthreads();
    if (threadIdx.x == 0) {
        const unsigned long long s = part[0] + part[1] + part[2] + part[3];
        atomicAdd(&counts[(size_t)b * CSTRIDE], s);
    }
}

__global__ void finalize_kernel(const unsigned long long* __restrict__ counts,
                                float* __restrict__ out) {
    const int lane = threadIdx.x;
    float s = 0.0f;
    if (lane < NB) {
        const unsigned long long p = counts[(size_t)lane * CSTRIDE];
        const float inter = (float)(unsigned int)(p & 0xFFFFFFFFull);
        const float uni   = (float)(unsigned int)(p >> 32);
        s = inter / uni;
    }
    #pragma unroll
    for (int off = 32; off > 0; off >>= 1)
        s += __shfl_down(s, off, 64);
    if (lane == 0)
        out[0] = s / (float)NB;
}

extern "C" void kernel_launch(void* const* d_in, const int* in_sizes, int n_in,
                              void* d_out, int out_size, void* d_ws, size_t ws_size,
                              hipStream_t stream) {
    const float* yhat = (const float*)d_in[0];
    const int*   y    = (const int*)d_in[1];
    float*       out  = (float*)d_out;
    unsigned long long* counts = (unsigned long long*)d_ws;

    hipMemsetAsync(d_ws, 0, NB * CSTRIDE * sizeof(unsigned long long), stream);

    dim3 grid(128, NB, 1);
    iou_kernel<<<grid, 256, 0, stream>>>(yhat, y, counts);
    finalize_kernel<<<1, 64, 0, stream>>>(counts, out);
}

// Round 3
// 29.728 us; speedup vs baseline: 5.2755x; 1.2634x over previous
//
#include <hip/hip_runtime.h>

#define IMG_H 512
#define IMG_W 512
#define NB    32
#define HW    (IMG_H * IMG_W)
#define SEGS  32             // 16-px segments per row
#define RPB   8              // rows per block (256 threads / 32 segs)
#define GX    (IMG_H / RPB)  // 64 blocks in x
#define NPART GX             // partials per batch

// Each thread: one 16-pixel row segment. Wave = 2 full rows (32 segs each);
// horizontal halo columns come from __shfl of packed per-row masks.
__global__ __launch_bounds__(256) void iou_kernel(const float* __restrict__ yhat,
                                                  const int* __restrict__ y,
                                                  unsigned long long* __restrict__ part) {
    const int b   = blockIdx.y;
    const int t   = blockIdx.x * 256 + threadIdx.x;
    const int h   = t >> 5;                 // row
    const int seg = t & 31;
    const int wbase = seg << 4;             // *16

    const int* yb = y + (size_t)b * HW;

    // 18-bit extended column masks: bit 0 = col wbase-1, bits 1..16 = own 16 cols,
    // bit 17 = col wbase+16. AND identity=1 (erode +inf border), OR identity=0.
    unsigned and1 = 0x3FFFFu, or1 = 0u, and2 = 0x3FFFFu, or2 = 0u;
    unsigned vmask = 0x3FFFFu;
    if (seg == 0)        vmask &= ~1u;          // image-left border
    if (seg == SEGS - 1) vmask &= ~(1u << 17);  // image-right border
    const unsigned inv = ~vmask;

    const int lane  = threadIdx.x & 63;
    const int laneL = (lane + 63) & 63;
    const int laneR = (lane + 1) & 63;

    #pragma unroll
    for (int dr = -1; dr <= 1; ++dr) {
        const int r = h + dr;
        const bool rv = (r >= 0) && (r < IMG_H);
        unsigned m1 = 0u, m2 = 0u;
        if (rv) {
            const int* row = yb + r * IMG_W + wbase;
            const int4 w0 = *reinterpret_cast<const int4*>(row);
            const int4 w1 = *reinterpret_cast<const int4*>(row + 4);
            const int4 w2 = *reinterpret_cast<const int4*>(row + 8);
            const int4 w3 = *reinterpret_cast<const int4*>(row + 12);
            const int c[16] = {w0.x, w0.y, w0.z, w0.w, w1.x, w1.y, w1.z, w1.w,
                               w2.x, w2.y, w2.z, w2.w, w3.x, w3.y, w3.z, w3.w};
            #pragma unroll
            for (int j = 0; j < 16; ++j) {
                m1 |= ((c[j] == 1) ? 1u : 0u) << j;
                m2 |= ((c[j] == 2) ? 1u : 0u) << j;
            }
        }
        // All lanes shuffle (uniform); cross-row leakage at lane 31<->32 only hits
        // seg==0 / seg==31 bits which vmask kills (image border there).
        const unsigned mm = m1 | (m2 << 16);
        const unsigned ml = __shfl(mm, laneL, 64);
        const unsigned mr = __shfl(mm, laneR, 64);
        if (rv) {
            const unsigned ext1 = (m1 << 1) | ((ml >> 15) & 1u) | ((mr & 1u) << 17);
            const unsigned ext2 = (m2 << 1) | (ml >> 31) | (((mr >> 16) & 1u) << 17);
            and1 &= (ext1 | inv);  or1 |= (ext1 & vmask);
            and2 &= (ext2 | inv);  or2 |= (ext2 & vmask);
        }
    }

    // 3-wide combine: pixel j <- ext bits j, j+1, j+2. E naturally 16-bit.
    const unsigned E1 = and1 & (and1 >> 1) & (and1 >> 2);
    const unsigned E2 = and2 & (and2 >> 1) & (and2 >> 2);
    const unsigned D1 = or1  | (or1  >> 1) | (or1  >> 2);
    const unsigned D2 = or2  | (or2  >> 1) | (or2  >> 2);

    // Argmax over 3 channels -> class bitmasks P1, P2 (first-occurrence ties via strict >).
    const float* yh = yhat + (size_t)b * 3 * HW + (size_t)h * IMG_W + wbase;
    float A[16], Bv[16], Cv[16];
    #pragma unroll
    for (int q = 0; q < 4; ++q) {
        const float4 va = *reinterpret_cast<const float4*>(yh + 4 * q);
        const float4 vb = *reinterpret_cast<const float4*>(yh + HW + 4 * q);
        const float4 vc = *reinterpret_cast<const float4*>(yh + 2 * HW + 4 * q);
        A[4*q+0]=va.x; A[4*q+1]=va.y; A[4*q+2]=va.z; A[4*q+3]=va.w;
        Bv[4*q+0]=vb.x; Bv[4*q+1]=vb.y; Bv[4*q+2]=vb.z; Bv[4*q+3]=vb.w;
        Cv[4*q+0]=vc.x; Cv[4*q+1]=vc.y; Cv[4*q+2]=vc.z; Cv[4*q+3]=vc.w;
    }
    unsigned P1 = 0u, P2 = 0u;
    #pragma unroll
    for (int j = 0; j < 16; ++j) {
        int   p    = 0;
        float best = A[j];
        if (Bv[j] > best) { best = Bv[j]; p = 1; }
        if (Cv[j] > best) {               p = 2; }
        P1 |= ((p == 1) ? 1u : 0u) << j;
        P2 |= ((p == 2) ? 1u : 0u) << j;
    }

    // inter: dilated==prob && dilated!=0 ; dil = D2?2:(D1?1:0)
    const unsigned inter = (unsigned)__popc((D2 & P2) | (D1 & ~D2 & P1));
    // uni: eroded!=0 || prob!=0 ; ero nonzero iff E1|E2
    const unsigned uni   = (unsigned)__popc((E1 | E2 | P1 | P2) & 0xFFFFu);

    // Wave reduce of packed (uni<<32 | inter), then block reduce, one store per block.
    unsigned long long packed = (unsigned long long)inter | ((unsigned long long)uni << 32);
    #pragma unroll
    for (int off = 32; off > 0; off >>= 1)
        packed += __shfl_down(packed, off, 64);

    __shared__ unsigned long long wsum[4];
    const int wave = threadIdx.x >> 6;
    if ((threadIdx.x & 63) == 0) wsum[wave] = packed;
    __syncthreads();
    if (threadIdx.x == 0)
        part[(size_t)b * NPART + blockIdx.x] = wsum[0] + wsum[1] + wsum[2] + wsum[3];
}

__global__ void finalize_kernel(const unsigned long long* __restrict__ part,
                                float* __restrict__ out) {
    // 256 threads: 8 threads per batch, each sums 8 of the 64 partials.
    const int t = threadIdx.x;
    const int b = t >> 3;
    const int k = t & 7;
    unsigned long long s = 0ull;
    #pragma unroll
    for (int i = 0; i < 8; ++i)
        s += part[(size_t)b * NPART + k * 8 + i];
    s += __shfl_down(s, 4, 8);
    s += __shfl_down(s, 2, 8);
    s += __shfl_down(s, 1, 8);

    __shared__ float r[NB];
    if (k == 0) {
        const float inter = (float)(unsigned int)(s & 0xFFFFFFFFull);
        const float uni   = (float)(unsigned int)(s >> 32);
        r[b] = inter / uni;
    }
    __syncthreads();
    if (t < 32) {
        float v = r[t];
        #pragma unroll
        for (int off = 16; off > 0; off >>= 1)
            v += __shfl_down(v, off, 32);
        if (t == 0) out[0] = v / (float)NB;
    }
}

extern "C" void kernel_launch(void* const* d_in, const int* in_sizes, int n_in,
                              void* d_out, int out_size, void* d_ws, size_t ws_size,
                              hipStream_t stream) {
    const float* yhat = (const float*)d_in[0];
    const int*   y    = (const int*)d_in[1];
    float*       out  = (float*)d_out;
    unsigned long long* part = (unsigned long long*)d_ws;   // 32*64 u64 = 16 KB

    dim3 grid(GX, NB, 1);
    iou_kernel<<<grid, 256, 0, stream>>>(yhat, y, part);
    finalize_kernel<<<1, 256, 0, stream>>>(part, out);
}